// Round 6
// baseline (246.614 us; speedup 1.0000x reference)
//
#include <hip/hip_runtime.h>
#include <math.h>
#include <stdint.h>

#define S    256
#define GN   128

typedef __attribute__((ext_vector_type(8))) short  short8;   // 8 bf16
typedef __attribute__((ext_vector_type(4))) float  floatx4;  // MFMA C/D

// workspace layout (bytes)
#define WS_BHI 0          // ushort[4*5*64*8]  = 20480 B
#define WS_BLO 20480      // ushort[4*5*64*8]  = 20480 B
#define WS_RW1 40960      // ushort[2*4*64*8]  =  8192 B
#define WS_B2S 49152      // float

__device__ __forceinline__ unsigned short bf16_rtne(float f) {
    uint32_t u = __builtin_bit_cast(uint32_t, f);
    uint32_t r = (u + 0x7fffu + ((u >> 16) & 1u)) >> 16;
    return (unsigned short)r;
}
__device__ __forceinline__ unsigned short bf16_rhu(float f) {   // round-half-up, 2 ops
    return (unsigned short)((__builtin_bit_cast(uint32_t, f) + 0x8000u) >> 16);
}
__device__ __forceinline__ float bf16_to_f(unsigned short s) {
    uint32_t u = ((uint32_t)s) << 16;
    return __builtin_bit_cast(float, u);
}

// ---------- pre-pack kernel: weights -> bf16 hi/lo in MFMA fragment order ----
__global__ __launch_bounds__(256)
void nerf_prep(const float* __restrict__ f_w2, const float* __restrict__ f_b2,
               const float* __restrict__ s_w,  const float* __restrict__ s_b,
               const float* __restrict__ r_w1, unsigned char* __restrict__ ws)
{
    __shared__ float ws2[128];
    const int tid = threadIdx.x;
    if (tid < 128) {                       // ws2 = W2 @ s_w  (fp32)
        float acc = 0.0f;
        for (int n = 0; n < 64; ++n) acc += f_w2[tid * 64 + n] * s_w[n];
        ws2[tid] = acc;
    } else if (tid == 128) {               // b2s = b2 . s_w + s_b
        float acc = s_b[0];
        for (int n = 0; n < 64; ++n) acc += f_b2[n] * s_w[n];
        *(float*)(ws + WS_B2S) = acc;
    }
    __syncthreads();

    unsigned short* bhi = (unsigned short*)(ws + WS_BHI);
    unsigned short* blo = (unsigned short*)(ws + WS_BLO);
    for (int i = tid; i < 10240; i += 256) {
        int j = i & 7, L = (i >> 3) & 63, g = i >> 9;   // g = kc*5 + tn
        int tn = g % 5, kc = g / 5;
        int q = L >> 4, cc = L & 15;
        int k = kc * 32 + q * 8 + j;
        float val = (tn < 4) ? f_w2[k * 64 + tn * 16 + cc]
                             : ((cc == 0) ? ws2[k] : 0.0f);
        unsigned short hi = bf16_rtne(val);
        bhi[i] = hi;
        blo[i] = bf16_rtne(val - bf16_to_f(hi));
    }
    unsigned short* rw = (unsigned short*)(ws + WS_RW1);
    for (int i = tid; i < 4096; i += 256) {
        int j = i & 7, L = (i >> 3) & 63, g = i >> 9;   // g = ks*4 + tn
        int tn = g & 3, ks = g >> 2;
        int q = L >> 4, cc = L & 15;
        int k = ks * 32 + q * 8 + j;
        rw[i] = bf16_rtne(r_w1[k * 64 + tn * 16 + cc]);
    }
}

// ---------------------------- main kernel -----------------------------------
// (256,2): 256-VGPR budget. Phase B needs ~190 live regs; the (256,3)/170 cap
// in R4 caused 91 MB of scratch spill traffic. A-fragment generation kept in
// the scalar form verified in R4 (packed v_perm variant regressed absmax
// 0.0039 -> 0.0898 in R5 — reverted).
__global__ __launch_bounds__(256, 2)
void nerf_mfma(const float* __restrict__ rays_o,
               const float* __restrict__ rays_d,
               const float* __restrict__ grid,
               const float* __restrict__ f_w1,
               const float* __restrict__ f_b1,
               const float* __restrict__ f_b2,
               const float* __restrict__ r_w1,
               const float* __restrict__ r_b1,
               const float* __restrict__ r_w2,
               const float* __restrict__ r_b2,
               const unsigned char* __restrict__ ws,
               float* __restrict__ out)
{
    // fh: bf16 [256 rows][64], XOR-swizzled in 8-ushort groups: conflict-free b128
    __shared__ unsigned short fh[256 * 64];
    __shared__ float aLds[S];
    __shared__ float maskLds[S];
    __shared__ float distLds[S];
    __shared__ float sWaveSum[4];
    __shared__ float sPart[4][3];

    const int tid   = threadIdx.x;
    const int ray   = blockIdx.x;
    const int lane  = tid & 63;
    const int wv    = tid >> 6;
    const int q     = lane >> 4;
    const int c     = lane & 15;
    const int mbase = wv * 64;

    // ---------------- Phase A: geometry + grid sample (thread = sample) ------
    const float stop = 1.0f - 1.0f / (float)(S + 2);
    const float step = stop / (float)S;
    float u0 = (float)tid * step;
    float u1 = (float)(tid + 1) * step;
    float t    = (u0 < 0.5f) ? 2.0f * u0 : 1.0f / (2.0f - 2.0f * u0);
    float tn_  = (u1 < 0.5f) ? 2.0f * u1 : 1.0f / (2.0f - 2.0f * u1);
    float dist = tn_ - t;

    float ox = rays_o[ray * 3 + 0], oy = rays_o[ray * 3 + 1], oz = rays_o[ray * 3 + 2];
    float dxv = rays_d[ray * 3 + 0], dyv = rays_d[ray * 3 + 1], dzv = rays_d[ray * 3 + 2];

    float px = ox + dxv * t, py = oy + dyv * t, pz = oz + dzv * t;
    float nrm = sqrtf(px * px + py * py + pz * pz);
    float scale = (nrm <= 1.0f) ? 0.5f : (2.0f - 1.0f / nrm) / nrm * 0.5f;
    float cx = px * scale, cy = py * scale, cz = pz * scale;

    float ix = ((cx + 1.0f) * (float)GN - 1.0f) * 0.5f;
    float iy = ((cy + 1.0f) * (float)GN - 1.0f) * 0.5f;
    float iz = ((cz + 1.0f) * (float)GN - 1.0f) * 0.5f;
    float fx0 = floorf(ix), fy0 = floorf(iy), fz0 = floorf(iz);
    float fx = ix - fx0, fy = iy - fy0, fz = iz - fz0;
    int x0 = (int)fx0, y0 = (int)fy0, z0 = (int)fz0;

    float occ = 0.0f;
    #pragma unroll
    for (int dzc = 0; dzc < 2; ++dzc)
    #pragma unroll
    for (int dyc = 0; dyc < 2; ++dyc)
    #pragma unroll
    for (int dxc = 0; dxc < 2; ++dxc) {
        int xc = x0 + dxc, yc = y0 + dyc, zc = z0 + dzc;
        float w = (dxc ? fx : 1.0f - fx) * (dyc ? fy : 1.0f - fy) * (dzc ? fz : 1.0f - fz);
        if (xc >= 0 && xc < GN && yc >= 0 && yc < GN && zc >= 0 && zc < GN)
            occ += w * grid[(zc * GN + yc) * GN + xc];
    }
    bool maskA = occ > 0.01f;
    maskLds[tid] = maskA ? 1.0f : 0.0f;
    distLds[tid] = dist;

    // coords of the A-fragment rows this thread covers (intra-wave broadcast)
    float cxs[4], cys[4], czs[4];
    #pragma unroll
    for (int tm = 0; tm < 4; ++tm) {
        int src = tm * 16 + c;
        cxs[tm] = __shfl(cx, src, 64);
        cys[tm] = __shfl(cy, src, 64);
        czs[tm] = __shfl(cz, src, 64);
    }

    // ---------------- Phase B: feat GEMM + sigma column, no LDS, no barriers -
    floatx4 facc[4][4];
    floatx4 sacc[4];
    {
        float b2v[4];
        #pragma unroll
        for (int tn = 0; tn < 4; ++tn) b2v[tn] = f_b2[tn * 16 + c];
        #pragma unroll
        for (int tm = 0; tm < 4; ++tm) {
            #pragma unroll
            for (int tn = 0; tn < 4; ++tn) {
                floatx4 v; v[0] = b2v[tn]; v[1] = b2v[tn]; v[2] = b2v[tn]; v[3] = b2v[tn];
                facc[tm][tn] = v;
            }
            floatx4 z; z[0] = 0.0f; z[1] = 0.0f; z[2] = 0.0f; z[3] = 0.0f;
            sacc[tm] = z;
        }
    }

    const unsigned short* __restrict__ bhiP = (const unsigned short*)(ws + WS_BHI);
    const unsigned short* __restrict__ bloP = (const unsigned short*)(ws + WS_BLO);

    #pragma unroll 1
    for (int kc = 0; kc < 4; ++kc) {
        const int k0 = kc * 32 + q * 8;
        float w1x[8], w1y[8], w1z[8], b1v[8];
        *(float4*)(w1x)     = *(const float4*)(f_w1 + k0);
        *(float4*)(w1x + 4) = *(const float4*)(f_w1 + k0 + 4);
        *(float4*)(w1y)     = *(const float4*)(f_w1 + 128 + k0);
        *(float4*)(w1y + 4) = *(const float4*)(f_w1 + 128 + k0 + 4);
        *(float4*)(w1z)     = *(const float4*)(f_w1 + 256 + k0);
        *(float4*)(w1z + 4) = *(const float4*)(f_w1 + 256 + k0 + 4);
        *(float4*)(b1v)     = *(const float4*)(f_b1 + k0);
        *(float4*)(b1v + 4) = *(const float4*)(f_b1 + k0 + 4);

        // A fragments: layer-1 recomputed in-register, hi=trunc, lo=rhu
        short8 Ah[4], Al[4];
        #pragma unroll
        for (int tm = 0; tm < 4; ++tm) {
            #pragma unroll
            for (int j = 0; j < 8; ++j) {
                float h = b1v[j] + cxs[tm] * w1x[j] + cys[tm] * w1y[j] + czs[tm] * w1z[j];
                h = fmaxf(h, 0.0f);
                uint32_t u = __builtin_bit_cast(uint32_t, h);
                float hf = __builtin_bit_cast(float, u & 0xffff0000u);
                Ah[tm][j] = (short)(u >> 16);
                Al[tm][j] = (short)bf16_rhu(h - hf);
            }
        }
        // B fragments: straight dwordx4 loads, zero conversion
        const int bbase = (kc * 5) * 512 + lane * 8;
        #pragma unroll
        for (int tn = 0; tn < 5; ++tn) {
            short8 bh = *(const short8*)(bhiP + bbase + tn * 512);
            short8 bl = *(const short8*)(bloP + bbase + tn * 512);
            #pragma unroll
            for (int tm = 0; tm < 4; ++tm) {
                floatx4 acc = (tn < 4) ? facc[tm][tn] : sacc[tm];
                acc = __builtin_amdgcn_mfma_f32_16x16x32_bf16(Ah[tm], bh, acc, 0, 0, 0);
                acc = __builtin_amdgcn_mfma_f32_16x16x32_bf16(Al[tm], bh, acc, 0, 0, 0);
                acc = __builtin_amdgcn_mfma_f32_16x16x32_bf16(Ah[tm], bl, acc, 0, 0, 0);
                if (tn < 4) facc[tm][tn] = acc; else sacc[tm] = acc;
            }
        }
    }

    // ---------------- Phase C: feat -> fh (swizzled bf16); sigma -> aLds -----
    #pragma unroll
    for (int tm = 0; tm < 4; ++tm)
        #pragma unroll
        for (int tn = 0; tn < 4; ++tn)
            #pragma unroll
            for (int reg = 0; reg < 4; ++reg) {
                int m = mbase + tm * 16 + q * 4 + reg;
                int n = tn * 16 + c;
                int idx = m * 64 + (((n >> 3) ^ (m & 7)) << 3) + (n & 7);
                fh[idx] = bf16_rhu(facc[tm][tn][reg]);
            }

    {
        float b2s = *(const float*)(ws + WS_B2S);
        if (c == 0) {
            #pragma unroll
            for (int tm = 0; tm < 4; ++tm)
                #pragma unroll
                for (int reg = 0; reg < 4; ++reg) {
                    int m = mbase + tm * 16 + q * 4 + reg;
                    float sa = sacc[tm][reg] + b2s;
                    float sg = (maskLds[m] > 0.5f)
                             ? (fmaxf(sa, 0.0f) + __logf(1.0f + __expf(-fabsf(sa)))) : 0.0f;
                    aLds[m] = -sg * distLds[m];
                }
        }
    }
    __builtin_amdgcn_wave_barrier();

    // ---------------- transmittance scan -------------------------------------
    float av = aLds[tid];
    float v = av;
    #pragma unroll
    for (int off = 1; off < 64; off <<= 1) {
        float u2 = __shfl_up(v, off);
        if (lane >= off) v += u2;
    }
    if (lane == 63) sWaveSum[wv] = v;
    __syncthreads();
    float basev = 0.0f;
    #pragma unroll
    for (int w = 0; w < 4; ++w) basev += (w < wv) ? sWaveSum[w] : 0.0f;
    float excl = __shfl_up(v, 1);
    if (lane == 0) excl = 0.0f;
    float cum    = basev + excl;
    float trans  = __expf(cum);
    float weight = trans * (1.0f - __expf(av));
    bool  mask2  = maskA && (trans > 1e-4f);

    // ---------------- Phase D: rgb-hidden GEMM -------------------------------
    float hd[4];
    #pragma unroll
    for (int tn = 0; tn < 4; ++tn) {
        int n = tn * 16 + c;
        hd[tn] = r_b1[n] + dxv * r_w1[64 * 64 + n] + dyv * r_w1[65 * 64 + n] + dzv * r_w1[66 * 64 + n];
    }

    short8 afr[4][2];
    #pragma unroll
    for (int tm = 0; tm < 4; ++tm)
        #pragma unroll
        for (int ks = 0; ks < 2; ++ks) {
            int m = mbase + tm * 16 + c;
            int gl = ks * 4 + q;
            afr[tm][ks] = *(const short8*)&fh[m * 64 + ((gl ^ (m & 7)) << 3)];
        }

    floatx4 hacc[4][4];
    #pragma unroll
    for (int tm = 0; tm < 4; ++tm)
        #pragma unroll
        for (int tn = 0; tn < 4; ++tn) {
            floatx4 z; z[0] = 0.0f; z[1] = 0.0f; z[2] = 0.0f; z[3] = 0.0f;
            hacc[tm][tn] = z;
        }
    const unsigned short* __restrict__ rwP = (const unsigned short*)(ws + WS_RW1);
    #pragma unroll
    for (int ks = 0; ks < 2; ++ks)
        #pragma unroll
        for (int tn = 0; tn < 4; ++tn) {
            short8 rb = *(const short8*)(rwP + ((ks * 4 + tn) * 64 + lane) * 8);
            #pragma unroll
            for (int tm = 0; tm < 4; ++tm)
                hacc[tm][tn] = __builtin_amdgcn_mfma_f32_16x16x32_bf16(afr[tm][ks], rb, hacc[tm][tn], 0, 0, 0);
        }

    __builtin_amdgcn_wave_barrier();
    #pragma unroll
    for (int tm = 0; tm < 4; ++tm)
        #pragma unroll
        for (int tn = 0; tn < 4; ++tn)
            #pragma unroll
            for (int reg = 0; reg < 4; ++reg) {
                int m = mbase + tm * 16 + q * 4 + reg;
                int n = tn * 16 + c;
                float hv = fmaxf(hacc[tm][tn][reg] + hd[tn], 0.0f);
                int idx = m * 64 + (((n >> 3) ^ (m & 7)) << 3) + (n & 7);
                fh[idx] = bf16_rhu(hv);
            }
    __builtin_amdgcn_wave_barrier();

    // ---------------- Phase E: final 64->3 (thread = sample) -----------------
    float o0 = r_b2[0], o1 = r_b2[1], o2 = r_b2[2];
    const uint32_t* __restrict__ fr = (const uint32_t*)fh;
    #pragma unroll
    for (int gl = 0; gl < 8; ++gl) {
        int pg = gl ^ (tid & 7);
        uint4 pk = *(const uint4*)(fr + tid * 32 + pg * 4);
        uint32_t pw[4] = {pk.x, pk.y, pk.z, pk.w};
        #pragma unroll
        for (int tt = 0; tt < 4; ++tt) {
            float h0 = __builtin_bit_cast(float, pw[tt] << 16);
            float h1 = __builtin_bit_cast(float, pw[tt] & 0xffff0000u);
            int k = gl * 8 + 2 * tt;
            o0 += h0 * r_w2[k * 3 + 0] + h1 * r_w2[k * 3 + 3];
            o1 += h0 * r_w2[k * 3 + 1] + h1 * r_w2[k * 3 + 4];
            o2 += h0 * r_w2[k * 3 + 2] + h1 * r_w2[k * 3 + 5];
        }
    }
    float r = 0.0f, g = 0.0f, b = 0.0f;
    if (mask2) {
        r = weight / (1.0f + __expf(-o0));
        g = weight / (1.0f + __expf(-o1));
        b = weight / (1.0f + __expf(-o2));
    }

    #pragma unroll
    for (int off = 32; off > 0; off >>= 1) {
        r += __shfl_down(r, off);
        g += __shfl_down(g, off);
        b += __shfl_down(b, off);
    }
    if (lane == 0) { sPart[wv][0] = r; sPart[wv][1] = g; sPart[wv][2] = b; }
    __syncthreads();
    if (tid == 0) {
        out[ray * 3 + 0] = sPart[0][0] + sPart[1][0] + sPart[2][0] + sPart[3][0];
        out[ray * 3 + 1] = sPart[0][1] + sPart[1][1] + sPart[2][1] + sPart[3][1];
        out[ray * 3 + 2] = sPart[0][2] + sPart[1][2] + sPart[2][2] + sPart[3][2];
    }
}

extern "C" void kernel_launch(void* const* d_in, const int* in_sizes, int n_in,
                              void* d_out, int out_size, void* d_ws, size_t ws_size,
                              hipStream_t stream) {
    const int n_rays = in_sizes[0] / 3;   // 4096
    nerf_prep<<<1, 256, 0, stream>>>(
        (const float*)d_in[5], (const float*)d_in[6], (const float*)d_in[7],
        (const float*)d_in[8], (const float*)d_in[9], (unsigned char*)d_ws);
    nerf_mfma<<<n_rays, 256, 0, stream>>>(
        (const float*)d_in[0],  (const float*)d_in[1],  (const float*)d_in[2],
        (const float*)d_in[3],  (const float*)d_in[4],  (const float*)d_in[6],
        (const float*)d_in[9],  (const float*)d_in[10], (const float*)d_in[11],
        (const float*)d_in[12], (const unsigned char*)d_ws, (float*)d_out);
}

// Round 7
// 224.050 us; speedup vs baseline: 1.1007x; 1.1007x over previous
//
#include <hip/hip_runtime.h>
#include <math.h>
#include <stdint.h>

#define S    256
#define GN   128

typedef __attribute__((ext_vector_type(8))) short  short8;   // 8 bf16
typedef __attribute__((ext_vector_type(4))) float  floatx4;  // MFMA C/D

// workspace layout (bytes)
#define WS_BHI 0          // ushort[4*5*64*8]  = 20480 B
#define WS_BLO 20480      // ushort[4*5*64*8]  = 20480 B
#define WS_RW1 40960      // ushort[2*4*64*8]  =  8192 B
#define WS_B2S 49152      // float
#define WS_W1P 49216      // float4[128] interleaved {w1x,w1y,w1z,b1} = 2048 B

__device__ __forceinline__ unsigned short bf16_rtne(float f) {
    uint32_t u = __builtin_bit_cast(uint32_t, f);
    uint32_t r = (u + 0x7fffu + ((u >> 16) & 1u)) >> 16;
    return (unsigned short)r;
}
__device__ __forceinline__ unsigned short bf16_rhu(float f) {   // round-half-up
    return (unsigned short)((__builtin_bit_cast(uint32_t, f) + 0x8000u) >> 16);
}
__device__ __forceinline__ float bf16_to_f(unsigned short s) {
    uint32_t u = ((uint32_t)s) << 16;
    return __builtin_bit_cast(float, u);
}

// ---------- pre-pack kernel: weights -> bf16 hi/lo in MFMA fragment order ----
__global__ __launch_bounds__(256)
void nerf_prep(const float* __restrict__ f_w1, const float* __restrict__ f_b1,
               const float* __restrict__ f_w2, const float* __restrict__ f_b2,
               const float* __restrict__ s_w,  const float* __restrict__ s_b,
               const float* __restrict__ r_w1, unsigned char* __restrict__ ws)
{
    __shared__ float ws2[128];
    const int tid = threadIdx.x;
    if (tid < 128) {                       // ws2 = W2 @ s_w  (fp32)
        float acc = 0.0f;
        for (int n = 0; n < 64; ++n) acc += f_w2[tid * 64 + n] * s_w[n];
        ws2[tid] = acc;
    } else if (tid == 128) {               // b2s = b2 . s_w + s_b
        float acc = s_b[0];
        for (int n = 0; n < 64; ++n) acc += f_b2[n] * s_w[n];
        *(float*)(ws + WS_B2S) = acc;
    }
    // layer-1 interleaved pack: entry k = {w1x[k], w1y[k], w1z[k], b1[k]}
    {
        float* w1pk = (float*)(ws + WS_W1P);
        for (int k = tid; k < 128; k += 256) {
            w1pk[k * 4 + 0] = f_w1[k];
            w1pk[k * 4 + 1] = f_w1[128 + k];
            w1pk[k * 4 + 2] = f_w1[256 + k];
            w1pk[k * 4 + 3] = f_b1[k];
        }
    }
    __syncthreads();

    unsigned short* bhi = (unsigned short*)(ws + WS_BHI);
    unsigned short* blo = (unsigned short*)(ws + WS_BLO);
    for (int i = tid; i < 10240; i += 256) {
        int j = i & 7, L = (i >> 3) & 63, g = i >> 9;   // g = kc*5 + tn
        int tn = g % 5, kc = g / 5;
        int q = L >> 4, cc = L & 15;
        int k = kc * 32 + q * 8 + j;
        float val = (tn < 4) ? f_w2[k * 64 + tn * 16 + cc]
                             : ((cc == 0) ? ws2[k] : 0.0f);
        unsigned short hi = bf16_rtne(val);
        bhi[i] = hi;
        blo[i] = bf16_rtne(val - bf16_to_f(hi));
    }
    unsigned short* rw = (unsigned short*)(ws + WS_RW1);
    for (int i = tid; i < 4096; i += 256) {
        int j = i & 7, L = (i >> 3) & 63, g = i >> 9;   // g = ks*4 + tn
        int tn = g & 3, ks = g >> 2;
        int q = L >> 4, cc = L & 15;
        int k = ks * 32 + q * 8 + j;
        rw[i] = bf16_rtne(r_w1[k * 64 + tn * 16 + cc]);
    }
}

// ---------------------------- main kernel -----------------------------------
// (256,3): R6 showed total reg need ~ 92 VGPR + 80 AGPR = 172, just over the
// 170 cap -> R4 spilled. w1 staging moved to LDS (broadcast ds_read_b128 per j)
// cuts ~30 VGPRs so 3 blocks/CU fits with no spills. A-frag math kept in the
// exact scalar form verified in R4/R6 (packed v_perm variant failed in R5).
__global__ __launch_bounds__(256, 3)
void nerf_mfma(const float* __restrict__ rays_o,
               const float* __restrict__ rays_d,
               const float* __restrict__ grid,
               const float* __restrict__ f_b2,
               const float* __restrict__ r_w1,
               const float* __restrict__ r_b1,
               const float* __restrict__ r_w2,
               const float* __restrict__ r_b2,
               const unsigned char* __restrict__ ws,
               float* __restrict__ out)
{
    // fh: bf16 [256 rows][64], XOR-swizzled in 8-ushort groups: conflict-free b128
    __shared__ unsigned short fh[256 * 64];
    __shared__ float w1p[512];            // interleaved {w1x,w1y,w1z,b1} per k
    __shared__ float aLds[S];
    __shared__ float maskLds[S];
    __shared__ float distLds[S];
    __shared__ float sWaveSum[4];
    __shared__ float sPart[4][3];

    const int tid   = threadIdx.x;
    const int ray   = blockIdx.x;
    const int lane  = tid & 63;
    const int wv    = tid >> 6;
    const int q     = lane >> 4;
    const int c     = lane & 15;
    const int mbase = wv * 64;

    // stage layer-1 pack (2 KB) into LDS
    if (tid < 128) ((float4*)w1p)[tid] = ((const float4*)(ws + WS_W1P))[tid];

    // ---------------- Phase A: geometry + grid sample (thread = sample) ------
    const float stop = 1.0f - 1.0f / (float)(S + 2);
    const float step = stop / (float)S;
    float u0 = (float)tid * step;
    float u1 = (float)(tid + 1) * step;
    float t    = (u0 < 0.5f) ? 2.0f * u0 : 1.0f / (2.0f - 2.0f * u0);
    float tn_  = (u1 < 0.5f) ? 2.0f * u1 : 1.0f / (2.0f - 2.0f * u1);
    float dist = tn_ - t;

    float ox = rays_o[ray * 3 + 0], oy = rays_o[ray * 3 + 1], oz = rays_o[ray * 3 + 2];
    float dxv = rays_d[ray * 3 + 0], dyv = rays_d[ray * 3 + 1], dzv = rays_d[ray * 3 + 2];

    float px = ox + dxv * t, py = oy + dyv * t, pz = oz + dzv * t;
    float nrm = sqrtf(px * px + py * py + pz * pz);
    float scale = (nrm <= 1.0f) ? 0.5f : (2.0f - 1.0f / nrm) / nrm * 0.5f;
    float cx = px * scale, cy = py * scale, cz = pz * scale;

    float ix = ((cx + 1.0f) * (float)GN - 1.0f) * 0.5f;
    float iy = ((cy + 1.0f) * (float)GN - 1.0f) * 0.5f;
    float iz = ((cz + 1.0f) * (float)GN - 1.0f) * 0.5f;
    float fx0 = floorf(ix), fy0 = floorf(iy), fz0 = floorf(iz);
    float fx = ix - fx0, fy = iy - fy0, fz = iz - fz0;
    int x0 = (int)fx0, y0 = (int)fy0, z0 = (int)fz0;

    float occ = 0.0f;
    #pragma unroll
    for (int dzc = 0; dzc < 2; ++dzc)
    #pragma unroll
    for (int dyc = 0; dyc < 2; ++dyc)
    #pragma unroll
    for (int dxc = 0; dxc < 2; ++dxc) {
        int xc = x0 + dxc, yc = y0 + dyc, zc = z0 + dzc;
        float w = (dxc ? fx : 1.0f - fx) * (dyc ? fy : 1.0f - fy) * (dzc ? fz : 1.0f - fz);
        if (xc >= 0 && xc < GN && yc >= 0 && yc < GN && zc >= 0 && zc < GN)
            occ += w * grid[(zc * GN + yc) * GN + xc];
    }
    bool maskA = occ > 0.01f;
    maskLds[tid] = maskA ? 1.0f : 0.0f;
    distLds[tid] = dist;

    // coords of the A-fragment rows this thread covers (intra-wave broadcast)
    float cxs[4], cys[4], czs[4];
    #pragma unroll
    for (int tm = 0; tm < 4; ++tm) {
        int src = tm * 16 + c;
        cxs[tm] = __shfl(cx, src, 64);
        cys[tm] = __shfl(cy, src, 64);
        czs[tm] = __shfl(cz, src, 64);
    }
    __syncthreads();   // w1p staged

    // ---------------- Phase B: feat GEMM + sigma column ----------------------
    floatx4 facc[4][4];
    floatx4 sacc[4];
    {
        float b2v[4];
        #pragma unroll
        for (int tn = 0; tn < 4; ++tn) b2v[tn] = f_b2[tn * 16 + c];
        #pragma unroll
        for (int tm = 0; tm < 4; ++tm) {
            #pragma unroll
            for (int tn = 0; tn < 4; ++tn) {
                floatx4 v; v[0] = b2v[tn]; v[1] = b2v[tn]; v[2] = b2v[tn]; v[3] = b2v[tn];
                facc[tm][tn] = v;
            }
            floatx4 z; z[0] = 0.0f; z[1] = 0.0f; z[2] = 0.0f; z[3] = 0.0f;
            sacc[tm] = z;
        }
    }

    const unsigned short* __restrict__ bhiP = (const unsigned short*)(ws + WS_BHI);
    const unsigned short* __restrict__ bloP = (const unsigned short*)(ws + WS_BLO);

    #pragma unroll 1
    for (int kc = 0; kc < 4; ++kc) {
        // A fragments: layer-1 recomputed from LDS pack, hi=trunc, lo=rhu
        const float4* __restrict__ w1q = (const float4*)&w1p[(kc * 32 + q * 8) * 4];
        short8 Ah[4], Al[4];
        #pragma unroll
        for (int j = 0; j < 8; ++j) {
            float4 w = w1q[j];        // {w1x, w1y, w1z, b1} broadcast b128
            #pragma unroll
            for (int tm = 0; tm < 4; ++tm) {
                float h = w.w + cxs[tm] * w.x + cys[tm] * w.y + czs[tm] * w.z;
                h = fmaxf(h, 0.0f);
                uint32_t u = __builtin_bit_cast(uint32_t, h);
                float hf = __builtin_bit_cast(float, u & 0xffff0000u);
                Ah[tm][j] = (short)(u >> 16);
                Al[tm][j] = (short)bf16_rhu(h - hf);
            }
        }
        // B fragments: straight dwordx4 loads, zero conversion
        const int bbase = (kc * 5) * 512 + lane * 8;
        #pragma unroll
        for (int tn = 0; tn < 5; ++tn) {
            short8 bh = *(const short8*)(bhiP + bbase + tn * 512);
            short8 bl = *(const short8*)(bloP + bbase + tn * 512);
            #pragma unroll
            for (int tm = 0; tm < 4; ++tm) {
                floatx4 acc = (tn < 4) ? facc[tm][tn] : sacc[tm];
                acc = __builtin_amdgcn_mfma_f32_16x16x32_bf16(Ah[tm], bh, acc, 0, 0, 0);
                acc = __builtin_amdgcn_mfma_f32_16x16x32_bf16(Al[tm], bh, acc, 0, 0, 0);
                acc = __builtin_amdgcn_mfma_f32_16x16x32_bf16(Ah[tm], bl, acc, 0, 0, 0);
                if (tn < 4) facc[tm][tn] = acc; else sacc[tm] = acc;
            }
        }
    }

    // ---------------- Phase C: feat -> fh (swizzled bf16); sigma -> aLds -----
    #pragma unroll
    for (int tm = 0; tm < 4; ++tm)
        #pragma unroll
        for (int tn = 0; tn < 4; ++tn)
            #pragma unroll
            for (int reg = 0; reg < 4; ++reg) {
                int m = mbase + tm * 16 + q * 4 + reg;
                int n = tn * 16 + c;
                int idx = m * 64 + (((n >> 3) ^ (m & 7)) << 3) + (n & 7);
                fh[idx] = bf16_rhu(facc[tm][tn][reg]);
            }

    {
        float b2s = *(const float*)(ws + WS_B2S);
        if (c == 0) {
            #pragma unroll
            for (int tm = 0; tm < 4; ++tm)
                #pragma unroll
                for (int reg = 0; reg < 4; ++reg) {
                    int m = mbase + tm * 16 + q * 4 + reg;
                    float sa = sacc[tm][reg] + b2s;
                    float sg = (maskLds[m] > 0.5f)
                             ? (fmaxf(sa, 0.0f) + __logf(1.0f + __expf(-fabsf(sa)))) : 0.0f;
                    aLds[m] = -sg * distLds[m];
                }
        }
    }
    __builtin_amdgcn_wave_barrier();

    // ---------------- transmittance scan -------------------------------------
    float av = aLds[tid];
    float v = av;
    #pragma unroll
    for (int off = 1; off < 64; off <<= 1) {
        float u2 = __shfl_up(v, off);
        if (lane >= off) v += u2;
    }
    if (lane == 63) sWaveSum[wv] = v;
    __syncthreads();
    float basev = 0.0f;
    #pragma unroll
    for (int w = 0; w < 4; ++w) basev += (w < wv) ? sWaveSum[w] : 0.0f;
    float excl = __shfl_up(v, 1);
    if (lane == 0) excl = 0.0f;
    float cum    = basev + excl;
    float trans  = __expf(cum);
    float weight = trans * (1.0f - __expf(av));
    bool  mask2  = maskA && (trans > 1e-4f);

    // ---------------- Phase D: rgb-hidden GEMM -------------------------------
    float hd[4];
    #pragma unroll
    for (int tn = 0; tn < 4; ++tn) {
        int n = tn * 16 + c;
        hd[tn] = r_b1[n] + dxv * r_w1[64 * 64 + n] + dyv * r_w1[65 * 64 + n] + dzv * r_w1[66 * 64 + n];
    }

    short8 afr[4][2];
    #pragma unroll
    for (int tm = 0; tm < 4; ++tm)
        #pragma unroll
        for (int ks = 0; ks < 2; ++ks) {
            int m = mbase + tm * 16 + c;
            int gl = ks * 4 + q;
            afr[tm][ks] = *(const short8*)&fh[m * 64 + ((gl ^ (m & 7)) << 3)];
        }

    floatx4 hacc[4][4];
    #pragma unroll
    for (int tm = 0; tm < 4; ++tm)
        #pragma unroll
        for (int tn = 0; tn < 4; ++tn) {
            floatx4 z; z[0] = 0.0f; z[1] = 0.0f; z[2] = 0.0f; z[3] = 0.0f;
            hacc[tm][tn] = z;
        }
    const unsigned short* __restrict__ rwP = (const unsigned short*)(ws + WS_RW1);
    #pragma unroll
    for (int ks = 0; ks < 2; ++ks)
        #pragma unroll
        for (int tn = 0; tn < 4; ++tn) {
            short8 rb = *(const short8*)(rwP + ((ks * 4 + tn) * 64 + lane) * 8);
            #pragma unroll
            for (int tm = 0; tm < 4; ++tm)
                hacc[tm][tn] = __builtin_amdgcn_mfma_f32_16x16x32_bf16(afr[tm][ks], rb, hacc[tm][tn], 0, 0, 0);
        }

    __builtin_amdgcn_wave_barrier();
    #pragma unroll
    for (int tm = 0; tm < 4; ++tm)
        #pragma unroll
        for (int tn = 0; tn < 4; ++tn)
            #pragma unroll
            for (int reg = 0; reg < 4; ++reg) {
                int m = mbase + tm * 16 + q * 4 + reg;
                int n = tn * 16 + c;
                float hv = fmaxf(hacc[tm][tn][reg] + hd[tn], 0.0f);
                int idx = m * 64 + (((n >> 3) ^ (m & 7)) << 3) + (n & 7);
                fh[idx] = bf16_rhu(hv);
            }
    __builtin_amdgcn_wave_barrier();

    // ---------------- Phase E: final 64->3 (thread = sample) -----------------
    float o0 = r_b2[0], o1 = r_b2[1], o2 = r_b2[2];
    const uint32_t* __restrict__ fr = (const uint32_t*)fh;
    #pragma unroll
    for (int gl = 0; gl < 8; ++gl) {
        int pg = gl ^ (tid & 7);
        uint4 pk = *(const uint4*)(fr + tid * 32 + pg * 4);
        uint32_t pw[4] = {pk.x, pk.y, pk.z, pk.w};
        #pragma unroll
        for (int tt = 0; tt < 4; ++tt) {
            float h0 = __builtin_bit_cast(float, pw[tt] << 16);
            float h1 = __builtin_bit_cast(float, pw[tt] & 0xffff0000u);
            int k = gl * 8 + 2 * tt;
            o0 += h0 * r_w2[k * 3 + 0] + h1 * r_w2[k * 3 + 3];
            o1 += h0 * r_w2[k * 3 + 1] + h1 * r_w2[k * 3 + 4];
            o2 += h0 * r_w2[k * 3 + 2] + h1 * r_w2[k * 3 + 5];
        }
    }
    float r = 0.0f, g = 0.0f, b = 0.0f;
    if (mask2) {
        r = weight / (1.0f + __expf(-o0));
        g = weight / (1.0f + __expf(-o1));
        b = weight / (1.0f + __expf(-o2));
    }

    #pragma unroll
    for (int off = 32; off > 0; off >>= 1) {
        r += __shfl_down(r, off);
        g += __shfl_down(g, off);
        b += __shfl_down(b, off);
    }
    if (lane == 0) { sPart[wv][0] = r; sPart[wv][1] = g; sPart[wv][2] = b; }
    __syncthreads();
    if (tid == 0) {
        out[ray * 3 + 0] = sPart[0][0] + sPart[1][0] + sPart[2][0] + sPart[3][0];
        out[ray * 3 + 1] = sPart[0][1] + sPart[1][1] + sPart[2][1] + sPart[3][1];
        out[ray * 3 + 2] = sPart[0][2] + sPart[1][2] + sPart[2][2] + sPart[3][2];
    }
}

extern "C" void kernel_launch(void* const* d_in, const int* in_sizes, int n_in,
                              void* d_out, int out_size, void* d_ws, size_t ws_size,
                              hipStream_t stream) {
    const int n_rays = in_sizes[0] / 3;   // 4096
    nerf_prep<<<1, 256, 0, stream>>>(
        (const float*)d_in[3], (const float*)d_in[4], (const float*)d_in[5],
        (const float*)d_in[6], (const float*)d_in[7], (const float*)d_in[8],
        (const float*)d_in[9], (unsigned char*)d_ws);
    nerf_mfma<<<n_rays, 256, 0, stream>>>(
        (const float*)d_in[0],  (const float*)d_in[1],  (const float*)d_in[2],
        (const float*)d_in[6],  (const float*)d_in[9],  (const float*)d_in[10],
        (const float*)d_in[11], (const float*)d_in[12],
        (const unsigned char*)d_ws, (float*)d_out);
}

// Round 8
// 190.369 us; speedup vs baseline: 1.2955x; 1.1769x over previous
//
#include <hip/hip_runtime.h>
#include <math.h>
#include <stdint.h>

#define S    256
#define GN   128

typedef __attribute__((ext_vector_type(8))) short  short8;   // 8 bf16
typedef __attribute__((ext_vector_type(4))) float  floatx4;  // MFMA C/D

// workspace layout (bytes)
#define WS_BHI 0          // ushort[4*4*64*8] = 16384 B  (f_w2 bf16, frag order)
#define WS_RW1 16384      // ushort[2*4*64*8] =  8192 B  (r_w1 bf16, frag order)
#define WS_B2S 24576      // float  (b2.s_w + s_b)
#define WS_WS2 24592      // float[128]  (W2 @ s_w, fp32)
#define WS_W1P 25104      // float4[128] interleaved {w1x,w1y,w1z,b1} = 2048 B

__device__ __forceinline__ unsigned short bf16_rtne(float f) {
    uint32_t u = __builtin_bit_cast(uint32_t, f);
    uint32_t r = (u + 0x7fffu + ((u >> 16) & 1u)) >> 16;
    return (unsigned short)r;
}
__device__ __forceinline__ unsigned short bf16_rhu(float f) {   // round-half-up
    return (unsigned short)((__builtin_bit_cast(uint32_t, f) + 0x8000u) >> 16);
}

// ---------- pre-pack kernel: weights -> bf16 in MFMA fragment order ----------
__global__ __launch_bounds__(256)
void nerf_prep(const float* __restrict__ f_w1, const float* __restrict__ f_b1,
               const float* __restrict__ f_w2, const float* __restrict__ f_b2,
               const float* __restrict__ s_w,  const float* __restrict__ s_b,
               const float* __restrict__ r_w1, unsigned char* __restrict__ ws)
{
    const int tid = threadIdx.x;
    if (tid < 128) {                       // ws2 = W2 @ s_w  (fp32) -> global
        float acc = 0.0f;
        for (int n = 0; n < 64; ++n) acc += f_w2[tid * 64 + n] * s_w[n];
        ((float*)(ws + WS_WS2))[tid] = acc;
    } else if (tid == 128) {               // b2s = b2 . s_w + s_b
        float acc = s_b[0];
        for (int n = 0; n < 64; ++n) acc += f_b2[n] * s_w[n];
        *(float*)(ws + WS_B2S) = acc;
    }
    // layer-1 interleaved pack: entry k = {w1x[k], w1y[k], w1z[k], b1[k]}
    {
        float* w1pk = (float*)(ws + WS_W1P);
        for (int k = tid; k < 128; k += 256) {
            w1pk[k * 4 + 0] = f_w1[k];
            w1pk[k * 4 + 1] = f_w1[128 + k];
            w1pk[k * 4 + 2] = f_w1[256 + k];
            w1pk[k * 4 + 3] = f_b1[k];
        }
    }

    unsigned short* bhi = (unsigned short*)(ws + WS_BHI);
    for (int i = tid; i < 8192; i += 256) {
        int j = i & 7, L = (i >> 3) & 63, g = i >> 9;   // g = kc*4 + tn
        int tn = g & 3, kc = g >> 2;
        int q = L >> 4, cc = L & 15;
        int k = kc * 32 + q * 8 + j;
        bhi[i] = bf16_rtne(f_w2[k * 64 + tn * 16 + cc]);
    }
    unsigned short* rw = (unsigned short*)(ws + WS_RW1);
    for (int i = tid; i < 4096; i += 256) {
        int j = i & 7, L = (i >> 3) & 63, g = i >> 9;   // g = ks*4 + tn
        int tn = g & 3, ks = g >> 2;
        int q = L >> 4, cc = L & 15;
        int k = ks * 32 + q * 8 + j;
        rw[i] = bf16_rtne(r_w1[k * 64 + tn * 16 + cc]);
    }
}

// ---------------------------- main kernel -----------------------------------
// R8 restructure: sigma computed on the VALU from fp32 layer-1 activations
// (h . ws2, full precision) instead of the 5th MFMA column with hi/lo bf16
// split. Feat GEMM is 1-term bf16 (feat is bf16-rounded for the rgb path
// anyway). Kills Al/blo/tn4: MFMAs 272->96, A-gen 9->6 ops/value, ~35 fewer
// VGPRs -> no spills at (256,3). A-frag math stays scalar (R5 lesson).
__global__ __launch_bounds__(256, 3)
void nerf_mfma(const float* __restrict__ rays_o,
               const float* __restrict__ rays_d,
               const float* __restrict__ grid,
               const float* __restrict__ f_b2,
               const float* __restrict__ r_w1,
               const float* __restrict__ r_b1,
               const float* __restrict__ r_w2,
               const float* __restrict__ r_b2,
               const unsigned char* __restrict__ ws,
               float* __restrict__ out)
{
    // fh: bf16 [256 rows][64], XOR-swizzled in 8-ushort groups: conflict-free b128
    __shared__ unsigned short fh[256 * 64];
    __shared__ float w1p[512];            // interleaved {w1x,w1y,w1z,b1} per k
    __shared__ float ws2L[128];           // W2 @ s_w (fp32)
    __shared__ float aLds[S];
    __shared__ float maskLds[S];
    __shared__ float distLds[S];
    __shared__ float sWaveSum[4];
    __shared__ float sPart[4][3];

    const int tid   = threadIdx.x;
    const int ray   = blockIdx.x;
    const int lane  = tid & 63;
    const int wv    = tid >> 6;
    const int q     = lane >> 4;
    const int c     = lane & 15;
    const int mbase = wv * 64;

    // stage layer-1 pack (2 KB) + ws2 (512 B) into LDS
    if (tid < 128) {
        ((float4*)w1p)[tid] = ((const float4*)(ws + WS_W1P))[tid];
        ws2L[tid] = ((const float*)(ws + WS_WS2))[tid];
    }

    // ---------------- Phase A: geometry + grid sample (thread = sample) ------
    const float stop = 1.0f - 1.0f / (float)(S + 2);
    const float step = stop / (float)S;
    float u0 = (float)tid * step;
    float u1 = (float)(tid + 1) * step;
    float t    = (u0 < 0.5f) ? 2.0f * u0 : 1.0f / (2.0f - 2.0f * u0);
    float tn_  = (u1 < 0.5f) ? 2.0f * u1 : 1.0f / (2.0f - 2.0f * u1);
    float dist = tn_ - t;

    float ox = rays_o[ray * 3 + 0], oy = rays_o[ray * 3 + 1], oz = rays_o[ray * 3 + 2];
    float dxv = rays_d[ray * 3 + 0], dyv = rays_d[ray * 3 + 1], dzv = rays_d[ray * 3 + 2];

    float px = ox + dxv * t, py = oy + dyv * t, pz = oz + dzv * t;
    float nrm = sqrtf(px * px + py * py + pz * pz);
    float scale = (nrm <= 1.0f) ? 0.5f : (2.0f - 1.0f / nrm) / nrm * 0.5f;
    float cx = px * scale, cy = py * scale, cz = pz * scale;

    float ix = ((cx + 1.0f) * (float)GN - 1.0f) * 0.5f;
    float iy = ((cy + 1.0f) * (float)GN - 1.0f) * 0.5f;
    float iz = ((cz + 1.0f) * (float)GN - 1.0f) * 0.5f;
    float fx0 = floorf(ix), fy0 = floorf(iy), fz0 = floorf(iz);
    float fx = ix - fx0, fy = iy - fy0, fz = iz - fz0;
    int x0 = (int)fx0, y0 = (int)fy0, z0 = (int)fz0;

    float occ = 0.0f;
    #pragma unroll
    for (int dzc = 0; dzc < 2; ++dzc)
    #pragma unroll
    for (int dyc = 0; dyc < 2; ++dyc)
    #pragma unroll
    for (int dxc = 0; dxc < 2; ++dxc) {
        int xc = x0 + dxc, yc = y0 + dyc, zc = z0 + dzc;
        float w = (dxc ? fx : 1.0f - fx) * (dyc ? fy : 1.0f - fy) * (dzc ? fz : 1.0f - fz);
        if (xc >= 0 && xc < GN && yc >= 0 && yc < GN && zc >= 0 && zc < GN)
            occ += w * grid[(zc * GN + yc) * GN + xc];
    }
    bool maskA = occ > 0.01f;
    maskLds[tid] = maskA ? 1.0f : 0.0f;
    distLds[tid] = dist;

    // coords of the A-fragment rows this thread covers (intra-wave broadcast)
    float cxs[4], cys[4], czs[4];
    #pragma unroll
    for (int tm = 0; tm < 4; ++tm) {
        int src = tm * 16 + c;
        cxs[tm] = __shfl(cx, src, 64);
        cys[tm] = __shfl(cy, src, 64);
        czs[tm] = __shfl(cz, src, 64);
    }
    __syncthreads();   // w1p / ws2L staged

    // ---------------- Phase B: feat GEMM (1-term bf16) + fp32 sigma dot ------
    floatx4 facc[4][4];
    {
        float b2v[4];
        #pragma unroll
        for (int tn = 0; tn < 4; ++tn) b2v[tn] = f_b2[tn * 16 + c];
        #pragma unroll
        for (int tm = 0; tm < 4; ++tm)
            #pragma unroll
            for (int tn = 0; tn < 4; ++tn) {
                floatx4 v; v[0] = b2v[tn]; v[1] = b2v[tn]; v[2] = b2v[tn]; v[3] = b2v[tn];
                facc[tm][tn] = v;
            }
    }
    float sig[4] = {0.0f, 0.0f, 0.0f, 0.0f};

    const unsigned short* __restrict__ bhiP = (const unsigned short*)(ws + WS_BHI);

    #pragma unroll 1
    for (int kc = 0; kc < 4; ++kc) {
        const int k0 = kc * 32 + q * 8;
        const float4* __restrict__ w1q = (const float4*)&w1p[k0 * 4];
        float ws2r[8];
        *(float4*)(ws2r)     = *(const float4*)&ws2L[k0];
        *(float4*)(ws2r + 4) = *(const float4*)&ws2L[k0 + 4];

        // A fragments: layer-1 recomputed from LDS pack; fp32 h feeds sigma dot
        short8 Ah[4];
        #pragma unroll
        for (int j = 0; j < 8; ++j) {
            float4 w = w1q[j];        // {w1x, w1y, w1z, b1} broadcast b128
            #pragma unroll
            for (int tm = 0; tm < 4; ++tm) {
                float h = w.w + cxs[tm] * w.x + cys[tm] * w.y + czs[tm] * w.z;
                h = fmaxf(h, 0.0f);
                sig[tm] += h * ws2r[j];
                Ah[tm][j] = (short)bf16_rhu(h);
            }
        }
        // B fragments: straight dwordx4 loads, zero conversion
        const int bbase = (kc * 4) * 512 + lane * 8;
        #pragma unroll
        for (int tn = 0; tn < 4; ++tn) {
            short8 bh = *(const short8*)(bhiP + bbase + tn * 512);
            #pragma unroll
            for (int tm = 0; tm < 4; ++tm)
                facc[tm][tn] = __builtin_amdgcn_mfma_f32_16x16x32_bf16(Ah[tm], bh, facc[tm][tn], 0, 0, 0);
        }
    }

    // ---------------- Phase C: feat -> fh (swizzled bf16); sigma -> aLds -----
    #pragma unroll
    for (int tm = 0; tm < 4; ++tm)
        #pragma unroll
        for (int tn = 0; tn < 4; ++tn)
            #pragma unroll
            for (int reg = 0; reg < 4; ++reg) {
                int m = mbase + tm * 16 + q * 4 + reg;
                int n = tn * 16 + c;
                int idx = m * 64 + (((n >> 3) ^ (m & 7)) << 3) + (n & 7);
                fh[idx] = bf16_rhu(facc[tm][tn][reg]);
            }

    {
        // reduce sigma partials over the 4 q-groups (k-chunks)
        #pragma unroll
        for (int tm = 0; tm < 4; ++tm) {
            sig[tm] += __shfl_xor(sig[tm], 16);
            sig[tm] += __shfl_xor(sig[tm], 32);
        }
        float b2s = *(const float*)(ws + WS_B2S);
        if (q == 0) {
            #pragma unroll
            for (int tm = 0; tm < 4; ++tm) {
                int m = mbase + tm * 16 + c;
                float sa = sig[tm] + b2s;
                float sg = (maskLds[m] > 0.5f)
                         ? (fmaxf(sa, 0.0f) + __logf(1.0f + __expf(-fabsf(sa)))) : 0.0f;
                aLds[m] = -sg * distLds[m];
            }
        }
    }
    __builtin_amdgcn_wave_barrier();

    // ---------------- transmittance scan -------------------------------------
    float av = aLds[tid];
    float v = av;
    #pragma unroll
    for (int off = 1; off < 64; off <<= 1) {
        float u2 = __shfl_up(v, off);
        if (lane >= off) v += u2;
    }
    if (lane == 63) sWaveSum[wv] = v;
    __syncthreads();
    float basev = 0.0f;
    #pragma unroll
    for (int w = 0; w < 4; ++w) basev += (w < wv) ? sWaveSum[w] : 0.0f;
    float excl = __shfl_up(v, 1);
    if (lane == 0) excl = 0.0f;
    float cum    = basev + excl;
    float trans  = __expf(cum);
    float weight = trans * (1.0f - __expf(av));
    bool  mask2  = maskA && (trans > 1e-4f);

    // ---------------- Phase D: rgb-hidden GEMM -------------------------------
    float hd[4];
    #pragma unroll
    for (int tn = 0; tn < 4; ++tn) {
        int n = tn * 16 + c;
        hd[tn] = r_b1[n] + dxv * r_w1[64 * 64 + n] + dyv * r_w1[65 * 64 + n] + dzv * r_w1[66 * 64 + n];
    }

    short8 afr[4][2];
    #pragma unroll
    for (int tm = 0; tm < 4; ++tm)
        #pragma unroll
        for (int ks = 0; ks < 2; ++ks) {
            int m = mbase + tm * 16 + c;
            int gl = ks * 4 + q;
            afr[tm][ks] = *(const short8*)&fh[m * 64 + ((gl ^ (m & 7)) << 3)];
        }

    floatx4 hacc[4][4];
    #pragma unroll
    for (int tm = 0; tm < 4; ++tm)
        #pragma unroll
        for (int tn = 0; tn < 4; ++tn) {
            floatx4 z; z[0] = 0.0f; z[1] = 0.0f; z[2] = 0.0f; z[3] = 0.0f;
            hacc[tm][tn] = z;
        }
    const unsigned short* __restrict__ rwP = (const unsigned short*)(ws + WS_RW1);
    #pragma unroll
    for (int ks = 0; ks < 2; ++ks)
        #pragma unroll
        for (int tn = 0; tn < 4; ++tn) {
            short8 rb = *(const short8*)(rwP + ((ks * 4 + tn) * 64 + lane) * 8);
            #pragma unroll
            for (int tm = 0; tm < 4; ++tm)
                hacc[tm][tn] = __builtin_amdgcn_mfma_f32_16x16x32_bf16(afr[tm][ks], rb, hacc[tm][tn], 0, 0, 0);
        }

    __builtin_amdgcn_wave_barrier();
    #pragma unroll
    for (int tm = 0; tm < 4; ++tm)
        #pragma unroll
        for (int tn = 0; tn < 4; ++tn)
            #pragma unroll
            for (int reg = 0; reg < 4; ++reg) {
                int m = mbase + tm * 16 + q * 4 + reg;
                int n = tn * 16 + c;
                float hv = fmaxf(hacc[tm][tn][reg] + hd[tn], 0.0f);
                int idx = m * 64 + (((n >> 3) ^ (m & 7)) << 3) + (n & 7);
                fh[idx] = bf16_rhu(hv);
            }
    __builtin_amdgcn_wave_barrier();

    // ---------------- Phase E: final 64->3 (thread = sample) -----------------
    float o0 = r_b2[0], o1 = r_b2[1], o2 = r_b2[2];
    const uint32_t* __restrict__ fr = (const uint32_t*)fh;
    #pragma unroll
    for (int gl = 0; gl < 8; ++gl) {
        int pg = gl ^ (tid & 7);
        uint4 pk = *(const uint4*)(fr + tid * 32 + pg * 4);
        uint32_t pw[4] = {pk.x, pk.y, pk.z, pk.w};
        #pragma unroll
        for (int tt = 0; tt < 4; ++tt) {
            float h0 = __builtin_bit_cast(float, pw[tt] << 16);
            float h1 = __builtin_bit_cast(float, pw[tt] & 0xffff0000u);
            int k = gl * 8 + 2 * tt;
            o0 += h0 * r_w2[k * 3 + 0] + h1 * r_w2[k * 3 + 3];
            o1 += h0 * r_w2[k * 3 + 1] + h1 * r_w2[k * 3 + 4];
            o2 += h0 * r_w2[k * 3 + 2] + h1 * r_w2[k * 3 + 5];
        }
    }
    float r = 0.0f, g = 0.0f, b = 0.0f;
    if (mask2) {
        r = weight / (1.0f + __expf(-o0));
        g = weight / (1.0f + __expf(-o1));
        b = weight / (1.0f + __expf(-o2));
    }

    #pragma unroll
    for (int off = 32; off > 0; off >>= 1) {
        r += __shfl_down(r, off);
        g += __shfl_down(g, off);
        b += __shfl_down(b, off);
    }
    if (lane == 0) { sPart[wv][0] = r; sPart[wv][1] = g; sPart[wv][2] = b; }
    __syncthreads();
    if (tid == 0) {
        out[ray * 3 + 0] = sPart[0][0] + sPart[1][0] + sPart[2][0] + sPart[3][0];
        out[ray * 3 + 1] = sPart[0][1] + sPart[1][1] + sPart[2][1] + sPart[3][1];
        out[ray * 3 + 2] = sPart[0][2] + sPart[1][2] + sPart[2][2] + sPart[3][2];
    }
}

extern "C" void kernel_launch(void* const* d_in, const int* in_sizes, int n_in,
                              void* d_out, int out_size, void* d_ws, size_t ws_size,
                              hipStream_t stream) {
    const int n_rays = in_sizes[0] / 3;   // 4096
    nerf_prep<<<1, 256, 0, stream>>>(
        (const float*)d_in[3], (const float*)d_in[4], (const float*)d_in[5],
        (const float*)d_in[6], (const float*)d_in[7], (const float*)d_in[8],
        (const float*)d_in[9], (unsigned char*)d_ws);
    nerf_mfma<<<n_rays, 256, 0, stream>>>(
        (const float*)d_in[0],  (const float*)d_in[1],  (const float*)d_in[2],
        (const float*)d_in[6],  (const float*)d_in[9],  (const float*)d_in[10],
        (const float*)d_in[11], (const float*)d_in[12],
        (const unsigned char*)d_ws, (float*)d_out);
}